// Round 1
// baseline (96.837 us; speedup 1.0000x reference)
//
#include <hip/hip_runtime.h>

// Problem constants (fixed by the reference): B=64, D=2048, UNITS=1024, NW=64.
// L (bucket capacity) is runtime-derived: in_sizes[3] / (UNITS*NW).
//
// out[b,u] = sum_i x[b,i] * W[u,i] + bias[u], where W[u,i] = w[k] iff
// indices[u,k,l] == i+1 for some l. Each i in [0,D) appears exactly once per
// unit u (the hash partitions positions into buckets), so scattering w[k]
// into a zero-initialized LDS row builds W[u,:] exactly, race-free.

#define B_DIM   64
#define D_DIM   2048
#define UNITS_N 1024
#define NW_N    64
#define U_PER_BLOCK 4
#define THREADS 512

__global__ __launch_bounds__(THREADS)
void EfficientHashedLinear_72043781423546_kernel(
    const float* __restrict__ x,        // (64, 2048)
    const float* __restrict__ w,        // (64,)
    const float* __restrict__ bias,     // (1024,)
    const int*   __restrict__ indices,  // (UNITS, NW, L) int32, 1-shifted, 0 = pad
    float*       __restrict__ out,      // (64, 1024)
    int L, int NWL)                     // NWL = NW * L
{
    __shared__ float rows[U_PER_BLOCK][D_DIM];   // 32 KB: W[u0+uu, :]
    __shared__ float w_lds[NW_N];

    const int tid = threadIdx.x;
    const int u0  = blockIdx.x * U_PER_BLOCK;

    // Phase 0: zero the weight rows, stage w.
    #pragma unroll
    for (int i = tid; i < U_PER_BLOCK * D_DIM; i += THREADS)
        ((float*)rows)[i] = 0.0f;
    if (tid < NW_N) w_lds[tid] = w[tid];
    __syncthreads();

    // Phase 1: scatter w[k] into the rows per index entry (coalesced int32 reads).
    const int total = U_PER_BLOCK * NWL;
    const int base  = u0 * NWL;
    for (int e = tid; e < total; e += THREADS) {
        int uu  = e / NWL;
        int r   = e - uu * NWL;
        int k   = r / L;
        int idx = indices[base + e];
        if (idx > 0) rows[uu][idx - 1] = w_lds[k];
    }
    __syncthreads();

    // Phase 2: out[b, u0..u0+3] = x[b,:] . rows[uu,:]
    // 8 waves; wave handles 8 batch rows; lanes split i; 4 FMAs per x load.
    const int wave = tid >> 6;
    const int lane = tid & 63;
    const int b0   = wave * 8;

    float acc[8][U_PER_BLOCK];
    #pragma unroll
    for (int bj = 0; bj < 8; ++bj)
        #pragma unroll
        for (int uu = 0; uu < U_PER_BLOCK; ++uu)
            acc[bj][uu] = 0.0f;

    #pragma unroll 4
    for (int step = 0; step < D_DIM / 64; ++step) {
        const int i = lane + step * 64;
        float rv[U_PER_BLOCK];
        #pragma unroll
        for (int uu = 0; uu < U_PER_BLOCK; ++uu)
            rv[uu] = rows[uu][i];
        #pragma unroll
        for (int bj = 0; bj < 8; ++bj) {
            float xv = x[(b0 + bj) * D_DIM + i];
            #pragma unroll
            for (int uu = 0; uu < U_PER_BLOCK; ++uu)
                acc[bj][uu] += xv * rv[uu];
        }
    }

    // Phase 3: reduce 64 lanes -> scalar, add bias, store.
    #pragma unroll
    for (int bj = 0; bj < 8; ++bj) {
        #pragma unroll
        for (int uu = 0; uu < U_PER_BLOCK; ++uu) {
            float v = acc[bj][uu];
            #pragma unroll
            for (int off = 32; off > 0; off >>= 1)
                v += __shfl_down(v, off, 64);
            if (lane == 0)
                out[(b0 + bj) * UNITS_N + (u0 + uu)] = v + bias[u0 + uu];
        }
    }
}

extern "C" void kernel_launch(void* const* d_in, const int* in_sizes, int n_in,
                              void* d_out, int out_size, void* d_ws, size_t ws_size,
                              hipStream_t stream) {
    const float* x       = (const float*)d_in[0];
    const float* w       = (const float*)d_in[1];
    const float* bias    = (const float*)d_in[2];
    const int*   indices = (const int*)d_in[3];
    float*       out     = (float*)d_out;

    const int L   = in_sizes[3] / (UNITS_N * NW_N);
    const int NWL = NW_N * L;

    dim3 grid(UNITS_N / U_PER_BLOCK);   // 256 blocks
    dim3 block(THREADS);                // 512 threads = 8 waves
    EfficientHashedLinear_72043781423546_kernel<<<grid, block, 0, stream>>>(
        x, w, bias, indices, out, L, NWL);
}